// Round 1
// baseline (380.256 us; speedup 1.0000x reference)
//
#include <hip/hip_runtime.h>

typedef __bf16 bf16_t;
typedef __attribute__((ext_vector_type(4))) __bf16 bf16x4;
typedef __attribute__((ext_vector_type(8))) __bf16 bf16x8;
typedef __attribute__((ext_vector_type(4))) float floatx4;

#define LN_EPS 1e-5f

// =====================================================================
// K1: c_all[17408][128] = [img|txt] @ [Wi|Wt]^T + (bi+bt)
// rows 0..16383  = query tokens (task*64+q), rows 16384..17407 = support (task*4+s)
// M=17408, N=128, K=2816 (2048 img + 768 txt). BM=64, BN=128, BK=32.
// 256 threads = 4 waves (2x2); each wave 32x64 = 2x4 mfma_f32_16x16x32_bf16.
// =====================================================================
#define K1_SA 40   // padded LDS stride (bf16 units); 40*2=80B is 16B-aligned
#define K1_SB 40

__global__ __launch_bounds__(256) void k1_gemm(
    const float* __restrict__ qimg, const float* __restrict__ qtxt,
    const float* __restrict__ simg, const float* __restrict__ stxt,
    const float* __restrict__ Wi,   const float* __restrict__ Wt,
    const float* __restrict__ bi,   const float* __restrict__ bt,
    float* __restrict__ c_all)
{
    __shared__ bf16_t lA[64 * K1_SA];
    __shared__ bf16_t lB[128 * K1_SB];

    const int tid  = threadIdx.x;
    const int m0   = blockIdx.x * 64;
    const bool isq = (m0 < 16384);
    const int rb   = isq ? m0 : (m0 - 16384);
    const float* Aimg = isq ? qimg : simg;
    const float* Atxt = isq ? qtxt : stxt;

    const int wid  = tid >> 6;
    const int lane = tid & 63;
    const int quad = lane >> 4;
    const int l16  = lane & 15;
    const int wr   = wid >> 1;   // 0..1: 32-row block
    const int wc   = wid & 1;    // 0..1: 64-col block

    const int srow = tid >> 3;   // 0..31 staging row
    const int sc4  = tid & 7;    // 0..7 float4 slot (32-wide K)

    floatx4 acc[2][4];
#pragma unroll
    for (int i = 0; i < 2; ++i)
#pragma unroll
        for (int j = 0; j < 4; ++j) acc[i][j] = (floatx4)0.f;

    for (int k0 = 0; k0 < 2816; k0 += 32) {
        const float* abase; const float* bbase; size_t lda, ldb;
        if (k0 < 2048) {
            abase = Aimg + (size_t)rb * 2048 + k0; lda = 2048;
            bbase = Wi + k0;                        ldb = 2048;
        } else {
            abase = Atxt + (size_t)rb * 768 + (k0 - 2048); lda = 768;
            bbase = Wt + (k0 - 2048);                       ldb = 768;
        }
        __syncthreads();   // previous iteration's frag reads done
#pragma unroll
        for (int p = 0; p < 2; ++p) {
            int r = srow + p * 32;
            float4 v = *(const float4*)(abase + (size_t)r * lda + sc4 * 4);
            bf16x4 pk; pk.x = (bf16_t)v.x; pk.y = (bf16_t)v.y;
                       pk.z = (bf16_t)v.z; pk.w = (bf16_t)v.w;
            *(bf16x4*)&lA[r * K1_SA + sc4 * 4] = pk;
        }
#pragma unroll
        for (int p = 0; p < 4; ++p) {
            int r = srow + p * 32;
            float4 v = *(const float4*)(bbase + (size_t)r * ldb + sc4 * 4);
            bf16x4 pk; pk.x = (bf16_t)v.x; pk.y = (bf16_t)v.y;
                       pk.z = (bf16_t)v.z; pk.w = (bf16_t)v.w;
            *(bf16x4*)&lB[r * K1_SB + sc4 * 4] = pk;
        }
        __syncthreads();
        bf16x8 af[2], bfr[4];
#pragma unroll
        for (int mt = 0; mt < 2; ++mt)
            af[mt] = *(const bf16x8*)&lA[(wr * 32 + mt * 16 + l16) * K1_SA + quad * 8];
#pragma unroll
        for (int nt = 0; nt < 4; ++nt)
            bfr[nt] = *(const bf16x8*)&lB[(wc * 64 + nt * 16 + l16) * K1_SB + quad * 8];
#pragma unroll
        for (int mt = 0; mt < 2; ++mt)
#pragma unroll
            for (int nt = 0; nt < 4; ++nt)
                acc[mt][nt] = __builtin_amdgcn_mfma_f32_16x16x32_bf16(
                    af[mt], bfr[nt], acc[mt][nt], 0, 0, 0);
    }
    // epilogue: D layout col=lane&15, row=quad*4+reg  [verified m89/m91]
#pragma unroll
    for (int nt = 0; nt < 4; ++nt) {
        int col = wc * 64 + nt * 16 + l16;
        float bias = bi[col] + bt[col];
#pragma unroll
        for (int mt = 0; mt < 2; ++mt)
#pragma unroll
            for (int r = 0; r < 4; ++r) {
                int row = wr * 32 + mt * 16 + quad * 4 + r;
                c_all[(size_t)(m0 + row) * 128 + col] = acc[mt][nt][r] + bias;
            }
    }
}

// =====================================================================
// K2: fused query tail. 64 tokens/block, 4 waves (16 tokens each).
//   LN1(c) -> @Wv^T+bv (MFMA) -> LN2 in-register -> @Wo^T+bo (MFMA) -> normalize
// Query attention is over seq-len 1 => softmax == 1 => ctx == v exactly.
// =====================================================================
#define K2_ST 136   // padded stride: 272B rows, 16B-aligned

__global__ __launch_bounds__(256) void k2_query(
    const float* __restrict__ c_all,
    const float* __restrict__ Wv, const float* __restrict__ bv,
    const float* __restrict__ Wo, const float* __restrict__ bo,
    const float* __restrict__ g1, const float* __restrict__ b1,
    const float* __restrict__ g2, const float* __restrict__ b2,
    float* __restrict__ qn)
{
    __shared__ bf16_t tT[64 * K2_ST];    // token tile (c' then v')
    __shared__ bf16_t tW[128 * K2_ST];   // Wv then Wo

    const int tid  = threadIdx.x;
    const int wid  = tid >> 6;
    const int lane = tid & 63;
    const int quad = lane >> 4;
    const int l16  = lane & 15;
    const int t0   = blockIdx.x * 64;
    const int r0   = wid * 16;

    float bvr[8], g2r[8], b2r[8], bor[8];
#pragma unroll
    for (int nt = 0; nt < 8; ++nt) {
        int col = nt * 16 + l16;
        bvr[nt] = bv[col]; g2r[nt] = g2[col]; b2r[nt] = b2[col]; bor[nt] = bo[col];
    }
    const float g1l = g1[lane], g1h = g1[64 + lane];
    const float b1l = b1[lane], b1h = b1[64 + lane];

    // LN1 on this wave's 16 token rows (wave-private rows of tT)
    for (int i = 0; i < 16; ++i) {
        int row = r0 + i;
        const float* src = c_all + (size_t)(t0 + row) * 128;
        float x0 = src[lane], x1 = src[64 + lane];
        float s = x0 + x1, q = x0 * x0 + x1 * x1;
#pragma unroll
        for (int m = 1; m < 64; m <<= 1) { s += __shfl_xor(s, m); q += __shfl_xor(q, m); }
        float mean = s * (1.f / 128.f);
        float var  = q * (1.f / 128.f) - mean * mean;
        float rs   = rsqrtf(var + LN_EPS);
        tT[row * K2_ST + lane]      = (bf16_t)((x0 - mean) * rs * g1l + b1l);
        tT[row * K2_ST + 64 + lane] = (bf16_t)((x1 - mean) * rs * g1h + b1h);
    }
    // stage Wv as bf16
#pragma unroll
    for (int i = 0; i < 16; ++i) {
        int idx = i * 1024 + tid * 4;
        int r = idx >> 7, cc = idx & 127;
        float4 v = *(const float4*)(Wv + idx);
        bf16x4 pk; pk.x = (bf16_t)v.x; pk.y = (bf16_t)v.y;
                   pk.z = (bf16_t)v.z; pk.w = (bf16_t)v.w;
        *(bf16x4*)&tW[r * K2_ST + cc] = pk;
    }
    __syncthreads();

    // v = c' @ Wv^T + bv
    floatx4 acc[8];
#pragma unroll
    for (int nt = 0; nt < 8; ++nt) acc[nt] = (floatx4)0.f;
#pragma unroll
    for (int ks = 0; ks < 4; ++ks) {
        bf16x8 a = *(const bf16x8*)&tT[(r0 + l16) * K2_ST + ks * 32 + quad * 8];
#pragma unroll
        for (int nt = 0; nt < 8; ++nt) {
            bf16x8 b = *(const bf16x8*)&tW[(nt * 16 + l16) * K2_ST + ks * 32 + quad * 8];
            acc[nt] = __builtin_amdgcn_mfma_f32_16x16x32_bf16(a, b, acc[nt], 0, 0, 0);
        }
    }
#pragma unroll
    for (int nt = 0; nt < 8; ++nt)
#pragma unroll
        for (int r = 0; r < 4; ++r) acc[nt][r] += bvr[nt];

    // LN2 in-register: lane's 4 rows are quad*4+r; row spans 8 nt in-lane x 16 lanes
#pragma unroll
    for (int r = 0; r < 4; ++r) {
        float s = 0.f, q = 0.f;
#pragma unroll
        for (int nt = 0; nt < 8; ++nt) { float x = acc[nt][r]; s += x; q += x * x; }
#pragma unroll
        for (int m = 1; m < 16; m <<= 1) { s += __shfl_xor(s, m); q += __shfl_xor(q, m); }
        float mean = s * (1.f / 128.f);
        float var  = q * (1.f / 128.f) - mean * mean;
        float rs   = rsqrtf(var + LN_EPS);
        int row = r0 + quad * 4 + r;
#pragma unroll
        for (int nt = 0; nt < 8; ++nt) {
            float y = (acc[nt][r] - mean) * rs * g2r[nt] + b2r[nt];
            tT[row * K2_ST + nt * 16 + l16] = (bf16_t)y;
        }
    }
    __syncthreads();          // everyone done reading Wv
    // stage Wo
#pragma unroll
    for (int i = 0; i < 16; ++i) {
        int idx = i * 1024 + tid * 4;
        int r = idx >> 7, cc = idx & 127;
        float4 v = *(const float4*)(Wo + idx);
        bf16x4 pk; pk.x = (bf16_t)v.x; pk.y = (bf16_t)v.y;
                   pk.z = (bf16_t)v.z; pk.w = (bf16_t)v.w;
        *(bf16x4*)&tW[r * K2_ST + cc] = pk;
    }
    __syncthreads();

    // qf = v' @ Wo^T + bo ;  qn = qf / max(||qf||, 1e-8)
#pragma unroll
    for (int nt = 0; nt < 8; ++nt) acc[nt] = (floatx4)0.f;
#pragma unroll
    for (int ks = 0; ks < 4; ++ks) {
        bf16x8 a = *(const bf16x8*)&tT[(r0 + l16) * K2_ST + ks * 32 + quad * 8];
#pragma unroll
        for (int nt = 0; nt < 8; ++nt) {
            bf16x8 b = *(const bf16x8*)&tW[(nt * 16 + l16) * K2_ST + ks * 32 + quad * 8];
            acc[nt] = __builtin_amdgcn_mfma_f32_16x16x32_bf16(a, b, acc[nt], 0, 0, 0);
        }
    }
#pragma unroll
    for (int r = 0; r < 4; ++r) {
        float q = 0.f;
#pragma unroll
        for (int nt = 0; nt < 8; ++nt) {
            float x = acc[nt][r] + bor[nt]; acc[nt][r] = x; q += x * x;
        }
#pragma unroll
        for (int m = 1; m < 16; m <<= 1) q += __shfl_xor(q, m);
        float inv = 1.f / fmaxf(sqrtf(q), 1e-8f);
        int row = t0 + r0 + quad * 4 + r;
#pragma unroll
        for (int nt = 0; nt < 8; ++nt)
            qn[(size_t)row * 128 + nt * 16 + l16] = acc[nt][r] * inv;
    }
}

// =====================================================================
// K3: support path, 1 block = 1 task (4 tokens, full attention), 4 waves.
// =====================================================================
__global__ __launch_bounds__(256) void k3_support(
    const float* __restrict__ c_all,
    const float* __restrict__ Wq, const float* __restrict__ bq,
    const float* __restrict__ Wk, const float* __restrict__ bk,
    const float* __restrict__ Wv, const float* __restrict__ bv,
    const float* __restrict__ Wo, const float* __restrict__ bo,
    const float* __restrict__ g1, const float* __restrict__ b1,
    const float* __restrict__ g2, const float* __restrict__ b2,
    float* __restrict__ pn)
{
    __shared__ float cs[4][128];
    __shared__ float qkv[3][4][128];
    __shared__ float att[4][4];
    __shared__ float ctx[4][128];

    const int tid  = threadIdx.x;
    const int wid  = tid >> 6;
    const int lane = tid & 63;
    const int task = blockIdx.x;

    { // LN1, one wave per token row
        const float* src = c_all + (size_t)(16384 + task * 4 + wid) * 128;
        float x0 = src[lane], x1 = src[64 + lane];
        float s = x0 + x1, q = x0 * x0 + x1 * x1;
#pragma unroll
        for (int m = 1; m < 64; m <<= 1) { s += __shfl_xor(s, m); q += __shfl_xor(q, m); }
        float mean = s * (1.f / 128.f);
        float var  = q * (1.f / 128.f) - mean * mean;
        float rs   = rsqrtf(var + LN_EPS);
        cs[wid][lane]      = (x0 - mean) * rs * g1[lane] + b1[lane];
        cs[wid][64 + lane] = (x1 - mean) * rs * g1[64 + lane] + b1[64 + lane];
    }
    __syncthreads();
    // q/k/v matvecs: 3*4*128 = 1536 outputs, 6 per thread
#pragma unroll
    for (int j = 0; j < 6; ++j) {
        int o = tid + j * 256;
        int wsel = o >> 9;
        int rem  = o & 511;
        int s = rem >> 7, n = rem & 127;
        const float* W = (wsel == 0) ? Wq : (wsel == 1) ? Wk : Wv;
        const float* B = (wsel == 0) ? bq : (wsel == 1) ? bk : bv;
        const float4* w4 = (const float4*)(W + n * 128);
        const float4* c4 = (const float4*)cs[s];
        float acc = 0.f;
#pragma unroll
        for (int k = 0; k < 32; ++k) {
            float4 a = c4[k], b = w4[k];
            acc += a.x * b.x + a.y * b.y + a.z * b.z + a.w * b.w;
        }
        qkv[wsel][s][n] = acc + B[n];
    }
    __syncthreads();
    if (tid < 16) {
        int i = tid >> 2, j = tid & 3;
        float acc = 0.f;
        for (int k = 0; k < 128; ++k) acc += qkv[0][i][k] * qkv[1][j][k];
        att[i][j] = acc * (float)(1.0 / (11.313708498984761 + 1e-8));
    }
    __syncthreads();
    if (tid < 4) {  // exact softmax -> +1e-10 -> renorm -> clip
        float s0 = att[tid][0], s1 = att[tid][1], s2 = att[tid][2], s3 = att[tid][3];
        float m = fmaxf(fmaxf(s0, s1), fmaxf(s2, s3));
        float e0 = expf(s0 - m), e1 = expf(s1 - m), e2 = expf(s2 - m), e3 = expf(s3 - m);
        float se = e0 + e1 + e2 + e3;
        float a0 = e0 / se + 1e-10f, a1 = e1 / se + 1e-10f;
        float a2 = e2 / se + 1e-10f, a3 = e3 / se + 1e-10f;
        float t = a0 + a1 + a2 + a3;
        att[tid][0] = fminf(fmaxf(a0 / t, 1e-7f), 1.f);
        att[tid][1] = fminf(fmaxf(a1 / t, 1e-7f), 1.f);
        att[tid][2] = fminf(fmaxf(a2 / t, 1e-7f), 1.f);
        att[tid][3] = fminf(fmaxf(a3 / t, 1e-7f), 1.f);
    }
    __syncthreads();
#pragma unroll
    for (int j = 0; j < 2; ++j) {  // ctx = a @ v
        int o = tid + j * 256;
        int s = o >> 7, n = o & 127;
        ctx[s][n] = att[s][0] * qkv[2][0][n] + att[s][1] * qkv[2][1][n]
                  + att[s][2] * qkv[2][2][n] + att[s][3] * qkv[2][3][n];
    }
    __syncthreads();
    { // LN2, wave per row -> cs (reuse)
        float x0 = ctx[wid][lane], x1 = ctx[wid][64 + lane];
        float s = x0 + x1, q = x0 * x0 + x1 * x1;
#pragma unroll
        for (int m = 1; m < 64; m <<= 1) { s += __shfl_xor(s, m); q += __shfl_xor(q, m); }
        float mean = s * (1.f / 128.f);
        float var  = q * (1.f / 128.f) - mean * mean;
        float rs   = rsqrtf(var + LN_EPS);
        cs[wid][lane]      = (x0 - mean) * rs * g2[lane] + b2[lane];
        cs[wid][64 + lane] = (x1 - mean) * rs * g2[64 + lane] + b2[64 + lane];
    }
    __syncthreads();
#pragma unroll
    for (int j = 0; j < 2; ++j) {  // pf = ctx' @ Wo^T + bo  (into ctx, reuse)
        int o = tid + j * 256;
        int s = o >> 7, n = o & 127;
        const float4* w4 = (const float4*)(Wo + n * 128);
        const float4* c4 = (const float4*)cs[s];
        float acc = 0.f;
#pragma unroll
        for (int k = 0; k < 32; ++k) {
            float4 a = c4[k], b = w4[k];
            acc += a.x * b.x + a.y * b.y + a.z * b.z + a.w * b.w;
        }
        ctx[s][n] = acc + bo[n];
    }
    __syncthreads();
    { // normalize rows, wave per row
        float x0 = ctx[wid][lane], x1 = ctx[wid][64 + lane];
        float q = x0 * x0 + x1 * x1;
#pragma unroll
        for (int m = 1; m < 64; m <<= 1) q += __shfl_xor(q, m);
        float inv = 1.f / fmaxf(sqrtf(q), 1e-8f);
        float* dst = pn + (size_t)(task * 4 + wid) * 128;
        dst[lane]      = x0 * inv;
        dst[64 + lane] = x1 * inv;
    }
}

// =====================================================================
// K4: logits[t][q][c] = 10 * qn[t][q] . pn[t][c]
// =====================================================================
__global__ __launch_bounds__(256) void k4_logits(
    const float* __restrict__ qn, const float* __restrict__ pn,
    float* __restrict__ out)
{
    __shared__ float pl[4][128];
    const int tid  = threadIdx.x;
    const int task = blockIdx.x;
#pragma unroll
    for (int j = 0; j < 2; ++j) {
        int o = tid + j * 256;
        int cc = o >> 7, k = o & 127;
        pl[cc][k] = pn[(size_t)(task * 4 + cc) * 128 + k];
    }
    __syncthreads();
    const int qi = tid >> 2, cc = tid & 3;
    const float4* q4 = (const float4*)(qn + (size_t)(task * 64 + qi) * 128);
    const float4* p4 = (const float4*)pl[cc];
    float acc = 0.f;
#pragma unroll
    for (int k = 0; k < 32; ++k) {
        float4 a = q4[k], b = p4[k];
        acc += a.x * b.x + a.y * b.y + a.z * b.z + a.w * b.w;
    }
    out[(size_t)task * 256 + qi * 4 + cc] = acc * 10.f;
}

// =====================================================================
extern "C" void kernel_launch(void* const* d_in, const int* in_sizes, int n_in,
                              void* d_out, int out_size, void* d_ws, size_t ws_size,
                              hipStream_t stream)
{
    const float* simg = (const float*)d_in[0];   // (256,4,2048)
    const float* stxt = (const float*)d_in[1];   // (256,4,768)
    // d_in[2] = support_labels: unused by the reference output
    const float* qimg = (const float*)d_in[3];   // (256,64,2048)
    const float* qtxt = (const float*)d_in[4];   // (256,64,768)
    const float* Wi = (const float*)d_in[5];
    const float* bi = (const float*)d_in[6];
    const float* Wt = (const float*)d_in[7];
    const float* bt = (const float*)d_in[8];
    const float* g1 = (const float*)d_in[9];
    const float* b1 = (const float*)d_in[10];
    const float* Wq = (const float*)d_in[11];
    const float* bq = (const float*)d_in[12];
    const float* Wk = (const float*)d_in[13];
    const float* bk = (const float*)d_in[14];
    const float* Wv = (const float*)d_in[15];
    const float* bv = (const float*)d_in[16];
    const float* g2 = (const float*)d_in[17];
    const float* b2 = (const float*)d_in[18];
    const float* Wo = (const float*)d_in[19];
    const float* bo = (const float*)d_in[20];
    float* out = (float*)d_out;

    // workspace layout (fp32): c_all 17408x128 | qn 16384x128 | pn 1024x128  (~17.8 MB)
    float* c_all = (float*)d_ws;
    float* qn    = c_all + (size_t)17408 * 128;
    float* pn    = qn    + (size_t)16384 * 128;

    k1_gemm<<<272, 256, 0, stream>>>(qimg, qtxt, simg, stxt, Wi, Wt, bi, bt, c_all);
    k2_query<<<256, 256, 0, stream>>>(c_all, Wv, bv, Wo, bo, g1, b1, g2, b2, qn);
    k3_support<<<256, 256, 0, stream>>>(c_all, Wq, bq, Wk, bk, Wv, bv, Wo, bo,
                                        g1, b1, g2, b2, pn);
    k4_logits<<<256, 256, 0, stream>>>(qn, pn, out);
}